// Round 1
// 1841.599 us; speedup vs baseline: 1.0692x; 1.0692x over previous
//
#include <hip/hip_runtime.h>

#define SEQ   2048
#define BATCH 512
#define ISZ   64
#define HSZ   128

// h stored as 4 K-blocks of 32 floats, each padded to 36 floats (144B, float4-aligned)
// so the 4 concurrent per-kg broadcast reads hit disjoint banks (mod-32 de-aliasing).
#define HPAD 36
#define HTOT (4*HPAD)   // 144

// Quad-lane butterfly add via DPP quad_perm — VALU pipe, NOT the LDS pipe.
// CTRL 0xB1 = [1,0,3,2] (xor 1), 0x4E = [2,3,0,1] (xor 2).
template<int CTRL>
__device__ __forceinline__ float qadd(float v) {
    int p = __builtin_amdgcn_update_dpp(0, __float_as_int(v), CTRL, 0xF, 0xF, true);
    return v + __int_as_float(p);
}

// One block (128 threads, 2 waves) per batch row.
// Lane: og = tid>>2 (0..31), kg = tid&3 (K-quarter).
// Thread computes 4 outputs {og+32i} over K-slice [kg*32,kg*32+32) of Wh and
// [kg*16,kg*16+16) of Wi; weights live in VGPRs (192 regs). Split-K combined
// with 2 DPP butterflies; each lane then owns output o = og+32*kg.
// Per step per wave: 8 ds_read_b128 (h) + 4 (x) + 1 ds_write — 4x less LDS
// traffic than the previous (1 output, K-half) mapping, which saturated the
// per-CU LDS pipe (192 instr/step/CU ~= the whole 1880-cycle step time).
__launch_bounds__(128, 1)
__global__ void rnn_fused(const float* __restrict__ x,
                          const float* __restrict__ Wh,
                          const float* __restrict__ bh,
                          const float* __restrict__ Wi,
                          const float* __restrict__ bi,
                          float* __restrict__ out)
{
    __shared__ __align__(16) float xbuf[2][32][ISZ];   // 16 KB
    __shared__ __align__(16) float hbuf[2][HTOT];      // 1.1 KB

    const int tid = threadIdx.x;
    const int b   = blockIdx.x;
    const int og  = tid >> 2;     // output group 0..31
    const int kg  = tid & 3;      // K-quarter 0..3

    // ---- weights into registers (one-time; Wh/Wi are L2/L3-resident) ----
    float whr[4][32];
    float wir[4][16];
    #pragma unroll
    for (int i = 0; i < 4; ++i) {
        const int o = og + 32*i;
        const float4* wp = (const float4*)(Wh + o*HSZ + kg*32);
        #pragma unroll
        for (int j = 0; j < 8; ++j) {
            float4 v = wp[j];
            whr[i][4*j+0]=v.x; whr[i][4*j+1]=v.y; whr[i][4*j+2]=v.z; whr[i][4*j+3]=v.w;
        }
        const float4* ip = (const float4*)(Wi + o*ISZ + kg*16);
        #pragma unroll
        for (int j = 0; j < 4; ++j) {
            float4 v = ip[j];
            wir[i][4*j+0]=v.x; wir[i][4*j+1]=v.y; wir[i][4*j+2]=v.z; wir[i][4*j+3]=v.w;
        }
    }
    const int   oown = og + 32*kg;            // output this lane stores
    const float bsel = bh[oown] + bi[oown];

    // ---- init h0 = 0 (pads included) ----
    for (int k = tid; k < 2*HTOT; k += 128) ((float*)hbuf)[k] = 0.f;

    // ---- stage x chunk 0 (row layout [t'][64], 4 float4 per thread) ----
    const int s = tid >> 3;   // 0..15
    const int c = tid & 7;    // 0..7  (float4 cols c and c+8)
    {
        const float* xr0 = x + ((size_t)(0  + s)*BATCH + b)*ISZ;
        const float* xr1 = x + ((size_t)(16 + s)*BATCH + b)*ISZ;
        float4 a0 = *(const float4*)(xr0 + c*4);
        float4 a1 = *(const float4*)(xr0 + (c+8)*4);
        float4 a2 = *(const float4*)(xr1 + c*4);
        float4 a3 = *(const float4*)(xr1 + (c+8)*4);
        *(float4*)&xbuf[0][s][c*4]        = a0;
        *(float4*)&xbuf[0][s][(c+8)*4]    = a1;
        *(float4*)&xbuf[0][16+s][c*4]     = a2;
        *(float4*)&xbuf[0][16+s][(c+8)*4] = a3;
    }
    __syncthreads();

    float4 p0 = make_float4(0.f,0.f,0.f,0.f), p1 = p0, p2 = p0, p3 = p0;
    float  hsel = 0.f;

    #pragma unroll 2
    for (int t = 0; t < SEQ; ++t) {
        const int cb  = (t >> 5) & 1;   // current x chunk buffer
        const int cur = t & 1;          // hbuf read buffer
        const int nxt = cur ^ 1;

        // x prefetch: issue at step%32==0, commit to LDS at ==16
        if ((t & 31) == 0 && t + 32 < SEQ) {
            const float* q0 = x + ((size_t)(t+32+s)*BATCH + b)*ISZ;
            const float* q1 = x + ((size_t)(t+48+s)*BATCH + b)*ISZ;
            p0 = *(const float4*)(q0 + c*4);
            p1 = *(const float4*)(q0 + (c+8)*4);
            p2 = *(const float4*)(q1 + c*4);
            p3 = *(const float4*)(q1 + (c+8)*4);
        }
        if ((t & 31) == 16 && t + 16 < SEQ) {
            const int nb = cb ^ 1;
            *(float4*)&xbuf[nb][s][c*4]        = p0;
            *(float4*)&xbuf[nb][s][(c+8)*4]    = p1;
            *(float4*)&xbuf[nb][16+s][c*4]     = p2;
            *(float4*)&xbuf[nb][16+s][(c+8)*4] = p3;
        }

        // ---- 4 quarter-dots: 4 outputs x (32 Wh + 16 Wi) terms ----
        float a0[4], a1[4], a2[4], a3[4];
        #pragma unroll
        for (int i = 0; i < 4; ++i) { a0[i]=0.f; a1[i]=0.f; a2[i]=0.f; a3[i]=0.f; }

        const float4* hb = (const float4*)(&hbuf[cur][kg*HPAD]);   // conflict-free broadcast
        #pragma unroll
        for (int j = 0; j < 8; ++j) {
            float4 hv = hb[j];
            #pragma unroll
            for (int i = 0; i < 4; ++i) {
                a0[i] += whr[i][4*j+0]*hv.x; a1[i] += whr[i][4*j+1]*hv.y;
                a2[i] += whr[i][4*j+2]*hv.z; a3[i] += whr[i][4*j+3]*hv.w;
            }
        }
        const float4* xv4 = (const float4*)(&xbuf[cb][t & 31][kg*16]);
        #pragma unroll
        for (int j = 0; j < 4; ++j) {
            float4 xv = xv4[j];
            #pragma unroll
            for (int i = 0; i < 4; ++i) {
                a0[i] += wir[i][4*j+0]*xv.x; a1[i] += wir[i][4*j+1]*xv.y;
                a2[i] += wir[i][4*j+2]*xv.z; a3[i] += wir[i][4*j+3]*xv.w;
            }
        }

        float d0 = (a0[0]+a1[0]) + (a2[0]+a3[0]);
        float d1 = (a0[1]+a1[1]) + (a2[1]+a3[1]);
        float d2 = (a0[2]+a1[2]) + (a2[2]+a3[2]);
        float d3 = (a0[3]+a1[3]) + (a2[3]+a3[3]);

        // split-K combine across the quad (kg in lane bits [1:0]) — VALU-pipe DPP
        d0 = qadd<0x4E>(qadd<0xB1>(d0));
        d1 = qadd<0x4E>(qadd<0xB1>(d1));
        d2 = qadd<0x4E>(qadd<0xB1>(d2));
        d3 = qadd<0x4E>(qadd<0xB1>(d3));

        // select own output (o = og + 32*kg) BEFORE tanh: one tanh per lane
        float v0  = (kg & 2) ? d2 : d0;
        float v1  = (kg & 2) ? d3 : d1;
        float acc = ((kg & 1) ? v1 : v0) + bsel;

        // tanh(x) = 1 - 2/(exp(2x)+1); saturates correctly at +/-inf
        float e = __expf(2.f * acc);
        hsel = 1.f - 2.f * __builtin_amdgcn_rcpf(e + 1.f);

        hbuf[nxt][kg*HPAD + og] = hsel;                       // 1 ds_write, all 64 lanes
        out[((size_t)t*BATCH + b)*HSZ + oown] = hsel;         // fire-and-forget

        // barrier WITHOUT vmcnt drain: only LDS ops must be visible; keep the
        // x prefetch loads and h_seq stores in flight across steps.
        asm volatile("s_waitcnt lgkmcnt(0)\n\ts_barrier" ::: "memory");
    }

    // final hidden state
    out[(size_t)SEQ*BATCH*HSZ + (size_t)b*HSZ + oown] = hsel;
}

extern "C" void kernel_launch(void* const* d_in, const int* in_sizes, int n_in,
                              void* d_out, int out_size, void* d_ws, size_t ws_size,
                              hipStream_t stream)
{
    const float* x  = (const float*)d_in[0];
    const float* Wh = (const float*)d_in[1];
    const float* bh = (const float*)d_in[2];
    const float* Wi = (const float*)d_in[3];
    const float* bi = (const float*)d_in[4];
    float* out = (float*)d_out;

    dim3 grid(BATCH);
    dim3 block(128);
    hipLaunchKernelGGL(rnn_fused, grid, block, 0, stream, x, Wh, bh, Wi, bi, out);
}